// Round 1
// baseline (76.516 us; speedup 1.0000x reference)
//
#include <hip/hip_runtime.h>

// 4-qubit quantum conv layer, closed-form simulation.
// Patch p = (b, r, c): x0=img[b,2r,2c], x1=[2r,2c+1], x2=[2r+1,2c], x3=[2r+1,2c+1].
// State index k: bit3(k)=qubit0, bit2=qubit1, bit1=qubit2, bit0=qubit3
// (matches reference (N,q0,q1,q2,q3) axis order).
//
// Phase after encoding: amp(k) = 0.25 * exp(i*phi(k)),
//   phi = sum_q (th_q/2)(2 b_q - 1) + sum_{i<j} (th_ij/2)(2 (b_i^b_j) - 1),
//   th_q = 0.785*x_q, th_ij = 0.785*x_i*x_j.
// Then RX(w_q) butterflies (stride 8>>q), then CNOT ring folded into sign masks:
//   Z0' = parity(b1,b2,b3), Z1' = parity(b0,b1), Z2' = parity(b0,b1,b2), Z3' = parity(all).
// Output channels (B,4,14,14) are [Z3, Z2, Z1, Z0].

#define NPATCH (4096 * 196)

__global__ __launch_bounds__(256) void qconv_kernel(
    const float* __restrict__ img,   // (4096,1,28,28)
    const float* __restrict__ w,     // (1,4)
    float* __restrict__ out)         // (4096,4,14,14)
{
    int p = blockIdx.x * blockDim.x + threadIdx.x;
    if (p >= NPATCH) return;

    int b   = p / 196;
    int rem = p - b * 196;
    int r   = rem / 14;
    int c   = rem - r * 14;

    // two float2 loads: (2r,2c..2c+1) and (2r+1,2c..2c+1); offsets even -> 8B aligned
    const float2* row0 = (const float2*)(img + b * 784 + (2 * r) * 28 + 2 * c);
    const float2* row1 = (const float2*)(img + b * 784 + (2 * r + 1) * 28 + 2 * c);
    float2 p0 = row0[0];
    float2 p1 = row1[0];
    float x0 = p0.x, x1 = p0.y, x2 = p1.x, x3 = p1.y;

    const float HR = 0.3925f;  // 0.785 / 2
    float t0 = x0 * HR, t1 = x1 * HR, t2 = x2 * HR, t3 = x3 * HR;
    float u01 = x0 * x1 * HR, u02 = x0 * x2 * HR, u03 = x0 * x3 * HR;
    float u12 = x1 * x2 * HR, u13 = x1 * x3 * HR, u23 = x2 * x3 * HR;

    float sr[16], si[16];
#pragma unroll
    for (int k = 0; k < 16; ++k) {
        const int b0 = (k >> 3) & 1, b1 = (k >> 2) & 1, b2 = (k >> 1) & 1, b3 = k & 1;
        float phi = (b0 ? t0 : -t0) + (b1 ? t1 : -t1) + (b2 ? t2 : -t2) + (b3 ? t3 : -t3)
                  + ((b0 ^ b1) ? u01 : -u01) + ((b0 ^ b2) ? u02 : -u02)
                  + ((b0 ^ b3) ? u03 : -u03) + ((b1 ^ b2) ? u12 : -u12)
                  + ((b1 ^ b3) ? u13 : -u13) + ((b2 ^ b3) ? u23 : -u23);
        float sn, cs;
        __sincosf(phi, &sn, &cs);
        sr[k] = 0.25f * cs;
        si[k] = 0.25f * sn;
    }

    // RX(w_q) on each qubit: new0 = c*a0 - i s*a1 ; new1 = -i s*a0 + c*a1
    float w0 = w[0], w1 = w[1], w2 = w[2], w3 = w[3];
#pragma unroll
    for (int q = 0; q < 4; ++q) {
        float wq = (q == 0) ? w0 : (q == 1) ? w1 : (q == 2) ? w2 : w3;
        float sq, cq;
        __sincosf(0.5f * wq, &sq, &cq);
        const int stride = 8 >> q;
#pragma unroll
        for (int k = 0; k < 16; ++k) {
            if (k & stride) continue;
            const int k1 = k | stride;
            float a0r = sr[k], a0i = si[k];
            float a1r = sr[k1], a1i = si[k1];
            sr[k]  = cq * a0r + sq * a1i;
            si[k]  = cq * a0i - sq * a1r;
            sr[k1] = cq * a1r + sq * a0i;
            si[k1] = cq * a1i - sq * a0r;
        }
    }

    // probabilities + Z expectations with CNOT-ring permutation folded into signs
    float e0 = 0.f, e1 = 0.f, e2 = 0.f, e3 = 0.f;
#pragma unroll
    for (int k = 0; k < 16; ++k) {
        const int b0 = (k >> 3) & 1, b1 = (k >> 2) & 1, b2 = (k >> 1) & 1, b3 = k & 1;
        float pk = sr[k] * sr[k] + si[k] * si[k];
        e0 += ((b1 ^ b2 ^ b3) ? -pk : pk);
        e1 += ((b0 ^ b1) ? -pk : pk);
        e2 += ((b0 ^ b1 ^ b2) ? -pk : pk);
        e3 += ((b0 ^ b1 ^ b2 ^ b3) ? -pk : pk);
    }

    // out[b, o, r, c]; channels = [Z3, Z2, Z1, Z0]
    float* o = out + b * (4 * 196) + r * 14 + c;
    o[0 * 196] = e3;
    o[1 * 196] = e2;
    o[2 * 196] = e1;
    o[3 * 196] = e0;
}

extern "C" void kernel_launch(void* const* d_in, const int* in_sizes, int n_in,
                              void* d_out, int out_size, void* d_ws, size_t ws_size,
                              hipStream_t stream) {
    const float* img = (const float*)d_in[0];
    const float* w   = (const float*)d_in[1];
    float* out       = (float*)d_out;

    const int threads = 256;
    const int blocks  = (NPATCH + threads - 1) / threads;  // 3136
    qconv_kernel<<<blocks, threads, 0, stream>>>(img, w, out);
}

// Round 2
// 73.744 us; speedup vs baseline: 1.0376x; 1.0376x over previous
//
#include <hip/hip_runtime.h>

// 4-qubit quantum conv layer, closed-form simulation (see round-0 derivation).
// This round: native v_sin/v_cos (revolutions, no range reduction needed since
// |phi| <= 3.93 rad = 0.625 rev), packed-fp32-friendly state layout
// (ext_vector_type(2), lane = qubit-0 bit), phase sharing phi(b0=1) =
// phi(b0=0) + 2*(t0 - G), and 1/16 normalization folded into the epilogue.
//
// State index k: bit3=qubit0(b0), bit2=b1, bit1=b2, bit0=b3.
// Vector slot m = k & 7 (b1,b2,b3); lane .x = b0=0, .y = b0=1.
// CNOT ring folded into parity sign masks:
//   Z0' = par(b1,b2,b3), Z1' = par(b0,b1), Z2' = par(b0,b1,b2), Z3' = par(all).
// Output channels (B,4,14,14) = [Z3, Z2, Z1, Z0].

typedef float v2f __attribute__((ext_vector_type(2)));

#define NPATCH (4096 * 196)
#define INV2PI 0.15915494309189535f

__device__ __forceinline__ void fast_sincos(float x, float* s, float* c) {
    float r = x * INV2PI;                 // revolutions; |r| <= ~0.63, in HW domain
    *s = __builtin_amdgcn_sinf(r);        // v_sin_f32: sin(r * 2pi)
    *c = __builtin_amdgcn_cosf(r);
}

__global__ __launch_bounds__(256) void qconv_kernel(
    const float* __restrict__ img,   // (4096,1,28,28)
    const float* __restrict__ w,     // (1,4)
    float* __restrict__ out)         // (4096,4,14,14)
{
    const int p = blockIdx.x * blockDim.x + threadIdx.x;   // grid covers exactly NPATCH

    const int b   = p / 196;
    const int rem = p - b * 196;
    const int r   = rem / 14;
    const int c   = rem - r * 14;

    const float2* row0 = (const float2*)(img + b * 784 + (2 * r) * 28 + 2 * c);
    const float2* row1 = (const float2*)(img + b * 784 + (2 * r + 1) * 28 + 2 * c);
    const float2 p0 = row0[0];
    const float2 p1 = row1[0];
    const float x0 = p0.x, x1 = p0.y, x2 = p1.x, x3 = p1.y;

    const float HR = 0.3925f;  // 0.785 / 2
    const float t0 = x0 * HR, t1 = x1 * HR, t2 = x2 * HR, t3 = x3 * HR;
    const float u01 = x0 * x1 * HR, u02 = x0 * x2 * HR, u03 = x0 * x3 * HR;
    const float u12 = x1 * x2 * HR, u13 = x1 * x3 * HR, u23 = x2 * x3 * HR;

    // ---- encoded-state phases: amp(k) = e^{i phi(k)} (1/4 factor folded out) ----
    v2f srv[8], siv[8];
#pragma unroll
    for (int m = 0; m < 8; ++m) {
        const int b1 = (m >> 2) & 1, b2 = (m >> 1) & 1, b3 = m & 1;
        const float G = (b1 ? u01 : -u01) + (b2 ? u02 : -u02) + (b3 ? u03 : -u03);
        const float K = ((b1 ^ b2) ? u12 : -u12) + ((b1 ^ b3) ? u13 : -u13)
                      + ((b2 ^ b3) ? u23 : -u23);
        const float L = (b1 ? t1 : -t1) + (b2 ? t2 : -t2) + (b3 ? t3 : -t3);
        const float phi0 = -t0 + L + G + K;             // b0 = 0
        const float phi1 = phi0 + 2.0f * (t0 - G);      // b0 = 1
        float s0, c0, s1, c1;
        fast_sincos(phi0, &s0, &c0);
        fast_sincos(phi1, &s1, &c1);
        srv[m].x = c0; srv[m].y = c1;
        siv[m].x = s0; siv[m].y = s1;
    }

    // ---- RX(w_q) layer ----
    const float w0 = w[0], w1 = w[1], w2 = w[2], w3 = w[3];

    // qubit 0: butterfly across the vector lanes (.x <-> .y)
    {
        float sq, cq;
        fast_sincos(0.5f * w0, &sq, &cq);
#pragma unroll
        for (int m = 0; m < 8; ++m) {
            const float a0r = srv[m].x, a0i = siv[m].x;
            const float a1r = srv[m].y, a1i = siv[m].y;
            srv[m].x = cq * a0r + sq * a1i;
            siv[m].x = cq * a0i - sq * a1r;
            srv[m].y = cq * a1r + sq * a0i;
            siv[m].y = cq * a1i - sq * a0r;
        }
    }

    // qubits 1..3: packed butterflies within m-space (strides 4, 2, 1)
#pragma unroll
    for (int q = 1; q < 4; ++q) {
        const float wq = (q == 1) ? w1 : (q == 2) ? w2 : w3;
        float sq, cq;
        fast_sincos(0.5f * wq, &sq, &cq);
        const int stride = 8 >> q;
#pragma unroll
        for (int m = 0; m < 8; ++m) {
            if (m & stride) continue;
            const int m1 = m | stride;
            const v2f A0r = srv[m], A0i = siv[m];
            const v2f A1r = srv[m1], A1i = siv[m1];
            srv[m]  = cq * A0r + sq * A1i;
            siv[m]  = cq * A0i - sq * A1r;
            srv[m1] = cq * A1r + sq * A0i;
            siv[m1] = cq * A1i - sq * A0r;
        }
    }

    // ---- probabilities + parity reductions (packed) ----
    v2f ta = {0.f, 0.f};  // sign = parity(b1)          -> e1
    v2f tb = {0.f, 0.f};  // sign = parity(b1^b2)       -> e2
    v2f tc = {0.f, 0.f};  // sign = parity(b1^b2^b3)    -> e0 (+) and e3 (-)
#pragma unroll
    for (int m = 0; m < 8; ++m) {
        const int b1 = (m >> 2) & 1, b2 = (m >> 1) & 1, b3 = m & 1;
        const v2f pv = srv[m] * srv[m] + siv[m] * siv[m];
        ta += (b1 ? -pv : pv);
        tb += ((b1 ^ b2) ? -pv : pv);
        tc += ((b1 ^ b2 ^ b3) ? -pv : pv);
    }
    const float SC = 0.0625f;  // (1/4 amplitude)^2 folded normalization
    const float e0 = (tc.x + tc.y) * SC;
    const float e1 = (ta.x - ta.y) * SC;
    const float e2 = (tb.x - tb.y) * SC;
    const float e3 = (tc.x - tc.y) * SC;

    // out[b, ch, r, c]; channels = [Z3, Z2, Z1, Z0]
    float* o = out + b * (4 * 196) + r * 14 + c;
    o[0 * 196] = e3;
    o[1 * 196] = e2;
    o[2 * 196] = e1;
    o[3 * 196] = e0;
}

extern "C" void kernel_launch(void* const* d_in, const int* in_sizes, int n_in,
                              void* d_out, int out_size, void* d_ws, size_t ws_size,
                              hipStream_t stream) {
    const float* img = (const float*)d_in[0];
    const float* w   = (const float*)d_in[1];
    float* out       = (float*)d_out;

    const int threads = 256;
    const int blocks  = NPATCH / threads;  // 3136, exact
    qconv_kernel<<<blocks, threads, 0, stream>>>(img, w, out);
}

// Round 3
// 73.288 us; speedup vs baseline: 1.0441x; 1.0062x over previous
//
#include <hip/hip_runtime.h>

// 4-qubit quantum conv layer, closed-form simulation (round-0 derivation).
// Round-3: all phases computed directly in REVOLUTIONS (1/2pi folded into the
// angle constants), feeding v_sin_f32/v_cos_f32 with no per-call scaling.
// |phi_rev| <= 0.63, well inside the HW domain.
//
// State index k: bit3=qubit0(b0), bit2=b1, bit1=b2, bit0=b3.
// Vector slot m (b1,b2,b3); lane .x = b0=0, .y = b0=1.
// CNOT ring folded into parity sign masks:
//   Z0' = par(b1,b2,b3), Z1' = par(b0,b1), Z2' = par(b0,b1,b2), Z3' = par(all).
// Output channels (B,4,14,14) = [Z3, Z2, Z1, Z0].

typedef float v2f __attribute__((ext_vector_type(2)));

#define NPATCH (4096 * 196)

__global__ __launch_bounds__(256) void qconv_kernel(
    const float* __restrict__ img,   // (4096,1,28,28)
    const float* __restrict__ w,     // (1,4)
    float* __restrict__ out)         // (4096,4,14,14)
{
    const int p = blockIdx.x * blockDim.x + threadIdx.x;   // grid == NPATCH exactly

    const int b   = p / 196;
    const int rem = p - b * 196;
    const int r   = rem / 14;
    const int c   = rem - r * 14;

    const float2* row0 = (const float2*)(img + b * 784 + (2 * r) * 28 + 2 * c);
    const float2* row1 = (const float2*)(img + b * 784 + (2 * r + 1) * 28 + 2 * c);
    const float2 p0 = row0[0];
    const float2 p1 = row1[0];
    const float x0 = p0.x, x1 = p0.y, x2 = p1.x, x3 = p1.y;

    // 0.785/2 * 1/(2pi): angle halves expressed in revolutions
    const float HRV = 0.785f * 0.5f * 0.15915494309189535f;
    const float t0 = x0 * HRV, t1 = x1 * HRV, t2 = x2 * HRV, t3 = x3 * HRV;
    const float u01 = x0 * x1 * HRV, u02 = x0 * x2 * HRV, u03 = x0 * x3 * HRV;
    const float u12 = x1 * x2 * HRV, u13 = x1 * x3 * HRV, u23 = x2 * x3 * HRV;

    // ---- encoded-state phases: amp(k) = e^{i*2pi*phi_rev(k)} (1/4 folded out) ----
    v2f srv[8], siv[8];
#pragma unroll
    for (int m = 0; m < 8; ++m) {
        const int b1 = (m >> 2) & 1, b2 = (m >> 1) & 1, b3 = m & 1;
        const float G = (b1 ? u01 : -u01) + (b2 ? u02 : -u02) + (b3 ? u03 : -u03);
        const float K = ((b1 ^ b2) ? u12 : -u12) + ((b1 ^ b3) ? u13 : -u13)
                      + ((b2 ^ b3) ? u23 : -u23);
        const float L = (b1 ? t1 : -t1) + (b2 ? t2 : -t2) + (b3 ? t3 : -t3);
        const float phi0 = -t0 + L + G + K;             // b0 = 0 (revolutions)
        const float phi1 = phi0 + 2.0f * (t0 - G);      // b0 = 1
        srv[m].x = __builtin_amdgcn_cosf(phi0);
        srv[m].y = __builtin_amdgcn_cosf(phi1);
        siv[m].x = __builtin_amdgcn_sinf(phi0);
        siv[m].y = __builtin_amdgcn_sinf(phi1);
    }

    // ---- RX(w_q) layer; half-angle in revolutions ----
    const float WRV = 0.5f * 0.15915494309189535f;
    const float w0 = w[0] * WRV, w1 = w[1] * WRV, w2 = w[2] * WRV, w3 = w[3] * WRV;

    // qubit 0: butterfly across the vector lanes (.x <-> .y)
    {
        const float cq = __builtin_amdgcn_cosf(w0);
        const float sq = __builtin_amdgcn_sinf(w0);
#pragma unroll
        for (int m = 0; m < 8; ++m) {
            const float a0r = srv[m].x, a0i = siv[m].x;
            const float a1r = srv[m].y, a1i = siv[m].y;
            srv[m].x = cq * a0r + sq * a1i;
            siv[m].x = cq * a0i - sq * a1r;
            srv[m].y = cq * a1r + sq * a0i;
            siv[m].y = cq * a1i - sq * a0r;
        }
    }

    // qubits 1..3: packed butterflies within m-space (strides 4, 2, 1)
#pragma unroll
    for (int q = 1; q < 4; ++q) {
        const float wq = (q == 1) ? w1 : (q == 2) ? w2 : w3;
        const float cq = __builtin_amdgcn_cosf(wq);
        const float sq = __builtin_amdgcn_sinf(wq);
        const int stride = 8 >> q;
#pragma unroll
        for (int m = 0; m < 8; ++m) {
            if (m & stride) continue;
            const int m1 = m | stride;
            const v2f A0r = srv[m], A0i = siv[m];
            const v2f A1r = srv[m1], A1i = siv[m1];
            srv[m]  = cq * A0r + sq * A1i;
            siv[m]  = cq * A0i - sq * A1r;
            srv[m1] = cq * A1r + sq * A0i;
            siv[m1] = cq * A1i - sq * A0r;
        }
    }

    // ---- probabilities + parity reductions (packed) ----
    v2f ta = {0.f, 0.f};  // sign = parity(b1)          -> e1
    v2f tb = {0.f, 0.f};  // sign = parity(b1^b2)       -> e2
    v2f tc = {0.f, 0.f};  // sign = parity(b1^b2^b3)    -> e0 / e3
#pragma unroll
    for (int m = 0; m < 8; ++m) {
        const int b1 = (m >> 2) & 1, b2 = (m >> 1) & 1, b3 = m & 1;
        const v2f pv = srv[m] * srv[m] + siv[m] * siv[m];
        ta += (b1 ? -pv : pv);
        tb += ((b1 ^ b2) ? -pv : pv);
        tc += ((b1 ^ b2 ^ b3) ? -pv : pv);
    }
    const float SC = 0.0625f;  // (1/4 amplitude)^2 normalization
    const float e0 = (tc.x + tc.y) * SC;
    const float e1 = (ta.x - ta.y) * SC;
    const float e2 = (tb.x - tb.y) * SC;
    const float e3 = (tc.x - tc.y) * SC;

    // out[b, ch, r, c]; channels = [Z3, Z2, Z1, Z0]; rem == r*14+c
    float* o = out + b * 784 + rem;
    o[0 * 196] = e3;
    o[1 * 196] = e2;
    o[2 * 196] = e1;
    o[3 * 196] = e0;
}

extern "C" void kernel_launch(void* const* d_in, const int* in_sizes, int n_in,
                              void* d_out, int out_size, void* d_ws, size_t ws_size,
                              hipStream_t stream) {
    const float* img = (const float*)d_in[0];
    const float* w   = (const float*)d_in[1];
    float* out       = (float*)d_out;

    const int threads = 256;
    const int blocks  = NPATCH / threads;  // 3136, exact
    qconv_kernel<<<blocks, threads, 0, stream>>>(img, w, out);
}